// Round 18
// baseline (650.100 us; speedup 1.0000x reference)
//
#include <hip/hip_runtime.h>
#include <cstdint>
#include <cstddef>

#define NN 50000
#define NE 1600000
#define XD 1025

typedef unsigned short ushortt;
typedef __attribute__((ext_vector_type(8))) short short8;
typedef __attribute__((ext_vector_type(4))) float f32x4;

__device__ __forceinline__ float relu_f(float v) { return v > 0.f ? v : 0.f; }
__device__ __forceinline__ float b2f(ushortt u) { return __uint_as_float(((unsigned)u) << 16); }
__device__ __forceinline__ float blo(unsigned u) { return __uint_as_float(u << 16); }
__device__ __forceinline__ float bhi(unsigned u) { return __uint_as_float(u & 0xffff0000u); }
__device__ __forceinline__ ushortt bf16rn(float f) {
    unsigned u = __float_as_uint(f);
    return (ushortt)((u + 0x7fffu + ((u >> 16) & 1u)) >> 16);
}
__device__ __forceinline__ void load_lds16(const void* g, void* l) {
    __builtin_amdgcn_global_load_lds(
        (const __attribute__((address_space(1))) void*)g,
        (__attribute__((address_space(3))) void*)l, 16, 0, 0);
}

// ================= bf16 MFMA GEMM =================
template <int ACT>
__global__ __launch_bounds__(256) void gemm_mfma(
    const ushortt* __restrict__ A, int lda,
    const ushortt* __restrict__ Bt,
    ushortt* __restrict__ C, int ldc,
    const float* __restrict__ bias,
    int M, int K)
{
    __shared__ ushortt As[128 * 32];
    __shared__ ushortt Bs[128 * 32];
    const int tid = threadIdx.x;
    const int w = tid >> 6, l = tid & 63;
    const int wr = w >> 1, wc = w & 1;
    const int brow = blockIdx.y << 7;
    const int bcol = blockIdx.x << 7;

    f32x4 acc[4][4] = {};

    const int rA0 = wr * 64 + (l & 15);
    const int rB0 = wc * 64 + (l & 15);
    const int kslot = l >> 4;

    for (int k0 = 0; k0 < K; k0 += 32) {
#pragma unroll
        for (int c = 0; c < 2; ++c) {
            int rl = c * 64 + w * 16 + (l >> 2);
            int csel = (l & 3) ^ (rl & 3);
            int gr = brow + rl; if (gr >= M) gr = M - 1;
            load_lds16(A + (size_t)gr * lda + k0 + csel * 8, &As[(c * 64 + w * 16) * 32]);
        }
#pragma unroll
        for (int c = 0; c < 2; ++c) {
            int rl = c * 64 + w * 16 + (l >> 2);
            int csel = (l & 3) ^ (rl & 3);
            load_lds16(Bt + (size_t)(bcol + rl) * K + k0 + csel * 8, &Bs[(c * 64 + w * 16) * 32]);
        }
        __syncthreads();

        short8 af[4], bf[4];
#pragma unroll
        for (int mi = 0; mi < 4; ++mi) {
            int row = rA0 + mi * 16;
            af[mi] = *(const short8*)&As[row * 32 + ((kslot ^ (row & 3)) << 3)];
        }
#pragma unroll
        for (int ni = 0; ni < 4; ++ni) {
            int row = rB0 + ni * 16;
            bf[ni] = *(const short8*)&Bs[row * 32 + ((kslot ^ (row & 3)) << 3)];
        }
#pragma unroll
        for (int mi = 0; mi < 4; ++mi)
#pragma unroll
            for (int ni = 0; ni < 4; ++ni)
                acc[mi][ni] = __builtin_amdgcn_mfma_f32_16x16x32_bf16(af[mi], bf[ni], acc[mi][ni], 0, 0, 0);
        __syncthreads();
    }

    const int cb = bcol + wc * 64 + (l & 15);
    const int rb = brow + wr * 64 + ((l >> 4) << 2);
#pragma unroll
    for (int mi = 0; mi < 4; ++mi) {
#pragma unroll
        for (int ni = 0; ni < 4; ++ni) {
            int col = cb + ni * 16;
            float bv = bias ? bias[col] : 0.f;
#pragma unroll
            for (int r = 0; r < 4; ++r) {
                int row = rb + mi * 16 + r;
                if (row < M) {
                    float v = acc[mi][ni][r] + bv;
                    if (ACT == 1) v = relu_f(v);
                    C[(size_t)row * ldc + col] = bf16rn(v);
                }
            }
        }
    }
}

// ================= per-head obar GEMM: 128x64 tile, 4 waves stacked in M ================
// obar[n, z*64+d] = sum_k pbar[n, z*256+k] * wv16[(z*64+d)*256+k] + ipb[512+z*64+d]
// grid (1, ceil(NN/128), 4)
__global__ __launch_bounds__(256) void gemm_obar(
    const ushortt* __restrict__ pbar,
    const ushortt* __restrict__ wv16,
    const float* __restrict__ ipb,
    ushortt* __restrict__ obar)
{
    __shared__ ushortt As[128 * 32];
    __shared__ ushortt Bs[64 * 32];
    const int tid = threadIdx.x;
    const int w = tid >> 6, l = tid & 63;
    const int z = blockIdx.z;
    const int brow = blockIdx.y << 7;
    const ushortt* Bt = wv16 + (size_t)z * 64 * 256;

    f32x4 acc[2][4] = {};
    const int rA0 = w * 32 + (l & 15);
    const int kslot = l >> 4;

    for (int k0 = 0; k0 < 256; k0 += 32) {
#pragma unroll
        for (int c = 0; c < 2; ++c) {
            int rl = c * 64 + w * 16 + (l >> 2);
            int csel = (l & 3) ^ (rl & 3);
            int gr = brow + rl; if (gr >= NN) gr = NN - 1;
            load_lds16(pbar + (size_t)gr * 1024 + z * 256 + k0 + csel * 8, &As[(c * 64 + w * 16) * 32]);
        }
        {
            int rl = w * 16 + (l >> 2);
            int csel = (l & 3) ^ (rl & 3);
            load_lds16(Bt + (size_t)rl * 256 + k0 + csel * 8, &Bs[(w * 16) * 32]);
        }
        __syncthreads();

        short8 af[2], bf[4];
#pragma unroll
        for (int mi = 0; mi < 2; ++mi) {
            int row = rA0 + mi * 16;
            af[mi] = *(const short8*)&As[row * 32 + ((kslot ^ (row & 3)) << 3)];
        }
#pragma unroll
        for (int ni = 0; ni < 4; ++ni) {
            int row = ni * 16 + (l & 15);
            bf[ni] = *(const short8*)&Bs[row * 32 + ((kslot ^ (row & 3)) << 3)];
        }
#pragma unroll
        for (int mi = 0; mi < 2; ++mi)
#pragma unroll
            for (int ni = 0; ni < 4; ++ni)
                acc[mi][ni] = __builtin_amdgcn_mfma_f32_16x16x32_bf16(af[mi], bf[ni], acc[mi][ni], 0, 0, 0);
        __syncthreads();
    }

    const int rb = brow + w * 32 + ((l >> 4) << 2);
#pragma unroll
    for (int mi = 0; mi < 2; ++mi) {
#pragma unroll
        for (int ni = 0; ni < 4; ++ni) {
            int col = ni * 16 + (l & 15);
            float bv = ipb[512 + z * 64 + col];
#pragma unroll
            for (int r = 0; r < 4; ++r) {
                int row = rb + mi * 16 + r;
                if (row < NN)
                    obar[(size_t)row * 256 + z * 64 + col] = bf16rn(acc[mi][ni][r] + bv);
            }
        }
    }
}

// ================= mega_a2: conv_x | conv_all(+wv) | gw | prep_T ================
// [0,25000) conv_x | [25000,26920) conv_all | [26920,39420) gw | [39420,39676) prep_T
__global__ __launch_bounds__(256) void mega_a2(
    const float* __restrict__ x,
    const float* __restrict__ w_go, const float* __restrict__ w_re,
    const float* __restrict__ w_me, const float* __restrict__ w2,
    const float* __restrict__ ipw,
    ushortt* __restrict__ o_go, ushortt* __restrict__ o_re,
    ushortt* __restrict__ o_me, ushortt* __restrict__ o_w2, ushortt* __restrict__ o_ip,
    ushortt* __restrict__ o_wv,
    ushortt* __restrict__ ago, ushortt* __restrict__ are, ushortt* __restrict__ ame,
    const float* __restrict__ w_gw, const float* __restrict__ b_gw, ushortt* __restrict__ p,
    const float* __restrict__ opw, const float* __restrict__ w1, float* __restrict__ T)
{
    const int bid = blockIdx.x;
    const int tid = threadIdx.x;
    if (bid < 25000) {
        long idx = bid * 256L + tid;
        int n = (int)(idx >> 7);
        int c8 = ((int)idx & 127) << 3;
        const float* src = x + (size_t)n * XD + c8;
        ushortt* dstp;
        if (c8 < 512) dstp = ago + (size_t)n * 512 + c8;
        else if (c8 < 768) dstp = are + (size_t)n * 256 + (c8 - 512);
        else dstp = ame + (size_t)n * 256 + (c8 - 768);
        ushort4 o1, o2;
        o1.x = bf16rn(src[0]); o1.y = bf16rn(src[1]); o1.z = bf16rn(src[2]); o1.w = bf16rn(src[3]);
        o2.x = bf16rn(src[4]); o2.y = bf16rn(src[5]); o2.z = bf16rn(src[6]); o2.w = bf16rn(src[7]);
        *(ushort4*)dstp = o1;
        *(ushort4*)(dstp + 4) = o2;
    } else if (bid < 26920) {
        int idx = (bid - 25000) * 256 + tid;
        if (idx < 131072) {
            int c = idx >> 9, r = idx & 511;
            o_go[idx] = bf16rn(w_go[r * 256 + c]);
        } else if (idx < 196608) {
            int j = idx - 131072; int c = j >> 8, r = j & 255;
            o_re[j] = bf16rn(w_re[r * 256 + c]);
        } else if (idx < 262144) {
            int j = idx - 196608; int c = j >> 8, r = j & 255;
            o_me[j] = bf16rn(w_me[r * 256 + c]);
        } else if (idx < 294912) {
            int j = idx - 262144; int c = j >> 8, r = j & 255;
            o_w2[j] = bf16rn(w2[r * 128 + c]);
        } else if (idx < 425984) {
            int j5 = idx - 294912;
            int j  = j5 & 7;
            int l  = (j5 >> 3) & 63;
            int qk = (j5 >> 9) & 1;
            int ni = (j5 >> 10) & 3;
            int kk = (j5 >> 12) & 7;
            int w  = (j5 >> 15) & 3;
            int row = qk * 256 + w * 64 + ni * 16 + (l & 15);
            int col = kk * 32 + ((l >> 4) << 3) + j;
            o_ip[j5] = bf16rn(ipw[(size_t)row * 256 + col]);
        } else if (idx < 491520) {
            int j6 = idx - 425984;
            o_wv[j6] = bf16rn(ipw[512 * 256 + j6]);
        }
    } else if (bid < 39420) {
        long idx = (bid - 26920) * 256L + tid;
        int n = (int)(idx >> 6);
        int c = ((int)idx & 63) << 2;
        float g = x[(size_t)n * XD + 1024];
        float4 w4 = *(const float4*)(w_gw + c);
        float4 b4 = *(const float4*)(b_gw + c);
        ushort4 r;
        r.x = bf16rn(relu_f(fmaf(g, w4.x, b4.x)));
        r.y = bf16rn(relu_f(fmaf(g, w4.y, b4.y)));
        r.z = bf16rn(relu_f(fmaf(g, w4.z, b4.z)));
        r.w = bf16rn(relu_f(fmaf(g, w4.w, b4.w)));
        *(ushort4*)(p + (size_t)n * 1024 + 768 + c) = r;
    } else {
        int d = bid - 39420, c = tid;
        float a = 0.f;
        for (int j = 0; j < 256; ++j)
            a = fmaf(opw[j * 256 + d], w1[j * 256 + c], a);
        T[d * 256 + c] = a;
    }
}

// ================= mega_b2: deg histogram + RANK capture, then branch GEMMs ================
__global__ __launch_bounds__(256) void mega_b2(
    const int* __restrict__ dst, int* __restrict__ deg, int* __restrict__ rank,
    const ushortt* __restrict__ ago, const ushortt* __restrict__ are, const ushortt* __restrict__ ame,
    const ushortt* __restrict__ wgo, const ushortt* __restrict__ wre, const ushortt* __restrict__ wme,
    const float* __restrict__ b_go, const float* __restrict__ b_re, const float* __restrict__ b_me,
    ushortt* __restrict__ p)
{
    __shared__ ushortt As[128 * 32];
    __shared__ ushortt Bs[128 * 32];
    const int bid = blockIdx.x;
    const int tid = threadIdx.x;

    if (bid < 1563) {
        int e = (bid * 256 + tid) * 4;
        if (e < NE) {
            int4 d = *(const int4*)(dst + e);
            int4 r;
            r.x = atomicAdd(&deg[d.x], 1);
            r.y = atomicAdd(&deg[d.y], 1);
            r.z = atomicAdd(&deg[d.z], 1);
            r.w = atomicAdd(&deg[d.w], 1);
            *(int4*)(rank + e) = r;
        }
        return;
    }

    const int t = bid - 1563;
    const int z = t / 782;
    const int r = t - z * 782;
    const int by = r >> 1;
    const int bx = r & 1;

    const ushortt* A; const ushortt* Bt; const float* bias; int K, lda, coff;
    if (z == 0)      { A = ago; Bt = wgo; bias = b_go; K = 512; lda = 512; coff = 0; }
    else if (z == 1) { A = are; Bt = wre; bias = b_re; K = 256; lda = 256; coff = 256; }
    else             { A = ame; Bt = wme; bias = b_me; K = 256; lda = 256; coff = 512; }

    const int w = tid >> 6, l = tid & 63;
    const int wr = w >> 1, wc = w & 1;
    const int brow = by << 7;
    const int bcol = bx << 7;

    f32x4 acc[4][4] = {};

    const int rA0 = wr * 64 + (l & 15);
    const int rB0 = wc * 64 + (l & 15);
    const int kslot = l >> 4;

    for (int k0 = 0; k0 < K; k0 += 32) {
#pragma unroll
        for (int c = 0; c < 2; ++c) {
            int rl = c * 64 + w * 16 + (l >> 2);
            int csel = (l & 3) ^ (rl & 3);
            int gr = brow + rl; if (gr >= NN) gr = NN - 1;
            load_lds16(A + (size_t)gr * lda + k0 + csel * 8, &As[(c * 64 + w * 16) * 32]);
        }
#pragma unroll
        for (int c = 0; c < 2; ++c) {
            int rl = c * 64 + w * 16 + (l >> 2);
            int csel = (l & 3) ^ (rl & 3);
            load_lds16(Bt + (size_t)(bcol + rl) * K + k0 + csel * 8, &Bs[(c * 64 + w * 16) * 32]);
        }
        __syncthreads();

        short8 af[4], bf[4];
#pragma unroll
        for (int mi = 0; mi < 4; ++mi) {
            int row = rA0 + mi * 16;
            af[mi] = *(const short8*)&As[row * 32 + ((kslot ^ (row & 3)) << 3)];
        }
#pragma unroll
        for (int ni = 0; ni < 4; ++ni) {
            int row = rB0 + ni * 16;
            bf[ni] = *(const short8*)&Bs[row * 32 + ((kslot ^ (row & 3)) << 3)];
        }
#pragma unroll
        for (int mi = 0; mi < 4; ++mi)
#pragma unroll
            for (int ni = 0; ni < 4; ++ni)
                acc[mi][ni] = __builtin_amdgcn_mfma_f32_16x16x32_bf16(af[mi], bf[ni], acc[mi][ni], 0, 0, 0);
        __syncthreads();
    }

    const int cb = bcol + wc * 64 + (l & 15);
    const int rb = brow + wr * 64 + ((l >> 4) << 2);
#pragma unroll
    for (int mi = 0; mi < 4; ++mi) {
#pragma unroll
        for (int ni = 0; ni < 4; ++ni) {
            int col = cb + ni * 16;
            float bv = bias[col];
#pragma unroll
            for (int rr = 0; rr < 4; ++rr) {
                int row = rb + mi * 16 + rr;
                if (row < NN)
                    p[(size_t)row * 1024 + coff + col] = bf16rn(relu_f(acc[mi][ni][rr] + bv));
            }
        }
    }
}

// ================= mega_c: Tt16 transpose | prep_bbig (opb@w1 only) | dinv ================
__global__ __launch_bounds__(256) void mega_c(
    const float* __restrict__ T, ushortt* __restrict__ Tt16,
    const float* __restrict__ opb, const float* __restrict__ w1,
    float* __restrict__ bbig,
    const int* __restrict__ deg, float* __restrict__ dinv)
{
    const int bid = blockIdx.x;
    const int tid = threadIdx.x;
    if (bid < 256) {
        // Tt16[c*256+d] = bf16(T[d*256+c]); c = bid, d = tid
        Tt16[bid * 256 + tid] = bf16rn(T[tid * 256 + bid]);
    } else if (bid == 256) {
        int c = tid;
        float a = 0.f;
        for (int j = 0; j < 256; ++j) a = fmaf(opb[j], w1[j * 256 + c], a);
        bbig[c] = a;
    } else {
        int n = (bid - 257) * 256 + tid;
        if (n < NN) dinv[n] = rsqrtf((float)deg[n] + 1.0f);
    }
}

// ================= scan kernels ================
__global__ __launch_bounds__(1024) void scan_blk(
    const int* __restrict__ deg, int* __restrict__ offs, int* __restrict__ btot, int N)
{
    __shared__ int wsum[16];
    const int tid = threadIdx.x;
    const int lane = tid & 63;
    const int w = tid >> 6;
    int i = blockIdx.x * 1024 + tid;
    int v = (i < N) ? deg[i] : 0;
    int x = v;
#pragma unroll
    for (int d = 1; d < 64; d <<= 1) {
        int t = __shfl_up(x, d);
        if (lane >= d) x += t;
    }
    if (lane == 63) wsum[w] = x;
    __syncthreads();
    if (w == 0 && lane < 16) {
        int y = wsum[lane];
#pragma unroll
        for (int d = 1; d < 16; d <<= 1) {
            int t = __shfl_up(y, d);
            if (lane >= d) y += t;
        }
        wsum[lane] = y;
    }
    __syncthreads();
    int waveoff = (w == 0) ? 0 : wsum[w - 1];
    if (i < N) offs[i] = waveoff + x - v;
    if (tid == 0) btot[blockIdx.x] = wsum[15];
}

__global__ __launch_bounds__(64) void scan_tot(int* __restrict__ btot, int nb)
{
    int t = threadIdx.x;
    int v = (t < nb) ? btot[t] : 0;
    int x = v;
#pragma unroll
    for (int d = 1; d < 64; d <<= 1) {
        int tt = __shfl_up(x, d);
        if (t >= d) x += tt;
    }
    if (t < nb) btot[t] = x - v;
    if (t == 63) btot[nb] = x;
}

__global__ __launch_bounds__(256) void scan_add(
    const int* __restrict__ btot, int* __restrict__ offs, int N, int nb)
{
    int i = blockIdx.x * 256 + threadIdx.x;
    if (i < N) offs[i] += btot[i >> 10];
    else if (i == N) offs[N] = btot[nb];
}

// ================= mega_d: atomic-free csr_fill | fused_attn_v7 ================
__global__ __launch_bounds__(256) void mega_d(
    const int* __restrict__ ei, const int* __restrict__ offs,
    const int* __restrict__ rank, int2* __restrict__ pk, const float* __restrict__ dinv,
    const ushortt* __restrict__ p,
    const ushortt* __restrict__ ipw_opt,
    const float* __restrict__ ipb,
    ushortt* __restrict__ pbar)
{
    __shared__ __align__(16) ushortt p_s[32 * 256];
    __shared__ float asum_s[8][4][4];

    const int bid = blockIdx.x;
    const int tid = threadIdx.x;

    if (bid < 1563) {
        int e = (bid * 256 + tid) * 4;
        if (e < NE) {
            int4 s4 = *(const int4*)(ei + e);
            int4 d4 = *(const int4*)(ei + NE + e);
            int4 r4 = *(const int4*)(rank + e);
            pk[offs[d4.x] + r4.x] = make_int2(s4.x, __float_as_int(dinv[s4.x] * dinv[d4.x]));
            pk[offs[d4.y] + r4.y] = make_int2(s4.y, __float_as_int(dinv[s4.y] * dinv[d4.y]));
            pk[offs[d4.z] + r4.z] = make_int2(s4.z, __float_as_int(dinv[s4.z] * dinv[d4.z]));
            pk[offs[d4.w] + r4.w] = make_int2(s4.w, __float_as_int(dinv[s4.w] * dinv[d4.w]));
        }
        return;
    }

    const int w = tid >> 6, l = tid & 63;
    const int nb = (bid - 1563) << 3;
    const size_t r0 = (size_t)nb * 4;

    {
        const int slot = l & 31;
#pragma unroll
        for (int c = 0; c < 4; ++c) {
            int row = w * 8 + c * 2 + (l >> 5);
            load_lds16(p + (r0 + row) * 256 + ((slot ^ (row & 7)) << 3),
                       &p_s[(w * 8 + c * 2) * 256]);
        }
    }
    __syncthreads();

    const int nq = w << 6;
    f32x4 aq[2][4] = {}, ak[2][4] = {};
    const int ar0 = l & 15, ar1 = ar0 + 16;
#pragma unroll
    for (int kk = 0; kk < 8; ++kk) {
        const int slot = (kk << 2) + (l >> 4);
        short8 a0 = *(const short8*)&p_s[ar0 * 256 + ((slot ^ (ar0 & 7)) << 3)];
        short8 a1 = *(const short8*)&p_s[ar1 * 256 + ((slot ^ (ar1 & 7)) << 3)];
        short8 bq[4], bk[4];
#pragma unroll
        for (int ni = 0; ni < 4; ++ni) {
            const size_t base = ((((size_t)(w * 8 + kk)) * 4 + ni) * 2) * 512 + (size_t)l * 8;
            bq[ni] = *(const short8*)&ipw_opt[base];
            bk[ni] = *(const short8*)&ipw_opt[base + 512];
        }
#pragma unroll
        for (int ni = 0; ni < 4; ++ni) {
            aq[0][ni] = __builtin_amdgcn_mfma_f32_16x16x32_bf16(a0, bq[ni], aq[0][ni], 0, 0, 0);
            aq[1][ni] = __builtin_amdgcn_mfma_f32_16x16x32_bf16(a1, bq[ni], aq[1][ni], 0, 0, 0);
            ak[0][ni] = __builtin_amdgcn_mfma_f32_16x16x32_bf16(a0, bk[ni], ak[0][ni], 0, 0, 0);
            ak[1][ni] = __builtin_amdgcn_mfma_f32_16x16x32_bf16(a1, bk[ni], ak[1][ni], 0, 0, 0);
        }
    }

    float bqv[4], bkv[4];
#pragma unroll
    for (int ni = 0; ni < 4; ++ni) {
        int col = nq + (ni << 4) + (l & 15);
        bqv[ni] = ipb[col];
        bkv[ni] = ipb[256 + col];
    }
#pragma unroll
    for (int mt = 0; mt < 2; ++mt) {
        float s[4][4] = {};
#pragma unroll
        for (int ni = 0; ni < 4; ++ni) {
            float qv[4], kv[4];
#pragma unroll
            for (int r = 0; r < 4; ++r) {
                qv[r] = aq[mt][ni][r] + bqv[ni];
                kv[r] = ak[mt][ni][r] + bkv[ni];
            }
#pragma unroll
            for (int ti = 0; ti < 4; ++ti)
#pragma unroll
                for (int tj = 0; tj < 4; ++tj)
                    s[ti][tj] = fmaf(qv[ti], kv[tj], s[ti][tj]);
        }
#pragma unroll
        for (int m = 1; m <= 8; m <<= 1)
#pragma unroll
            for (int ti = 0; ti < 4; ++ti)
#pragma unroll
                for (int tj = 0; tj < 4; ++tj)
                    s[ti][tj] += __shfl_xor(s[ti][tj], m);
        float asum[4] = {};
#pragma unroll
        for (int ti = 0; ti < 4; ++ti) {
            float v0 = s[ti][0] * 0.125f, v1 = s[ti][1] * 0.125f;
            float v2 = s[ti][2] * 0.125f, v3 = s[ti][3] * 0.125f;
            float m4 = fmaxf(fmaxf(v0, v1), fmaxf(v2, v3));
            float e0 = __expf(v0 - m4), e1 = __expf(v1 - m4);
            float e2 = __expf(v2 - m4), e3 = __expf(v3 - m4);
            float inv = 1.f / (e0 + e1 + e2 + e3);
            asum[0] = fmaf(e0, inv, asum[0]);
            asum[1] = fmaf(e1, inv, asum[1]);
            asum[2] = fmaf(e2, inv, asum[2]);
            asum[3] = fmaf(e3, inv, asum[3]);
        }
        if ((l & 15) == 0) {
            int node = mt * 4 + (l >> 4);
#pragma unroll
            for (int tj = 0; tj < 4; ++tj)
                asum_s[node][w][tj] = 0.25f * asum[tj];
        }
    }
    __syncthreads();

    {
        const int node = tid >> 5;
        const int c8 = (tid & 31) << 3;
        float f[4][8];
#pragma unroll
        for (int tj = 0; tj < 4; ++tj) {
            int row = node * 4 + tj;
            uint4 u = *(const uint4*)&p_s[row * 256 + (((c8 >> 3) ^ (row & 7)) << 3)];
            f[tj][0] = blo(u.x); f[tj][1] = bhi(u.x); f[tj][2] = blo(u.y); f[tj][3] = bhi(u.y);
            f[tj][4] = blo(u.z); f[tj][5] = bhi(u.z); f[tj][6] = blo(u.w); f[tj][7] = bhi(u.w);
        }
#pragma unroll
        for (int h = 0; h < 4; ++h) {
            float a0 = asum_s[node][h][0], a1 = asum_s[node][h][1];
            float a2 = asum_s[node][h][2], a3 = asum_s[node][h][3];
            ushortt res[8];
#pragma unroll
            for (int i = 0; i < 8; ++i)
                res[i] = bf16rn(a0 * f[0][i] + a1 * f[1][i] + a2 * f[2][i] + a3 * f[3][i]);
            *(uint4*)&pbar[(size_t)(nb + node) * 1024 + h * 256 + c8] = *(uint4*)res;
        }
    }
}

// ================= GCN gather F=256 ================
template <int ACT, int OUTBF>
__global__ __launch_bounds__(256) void gcn_gather256(
    const int* __restrict__ offs, const int2* __restrict__ pk,
    const ushortt* __restrict__ hw,
    const float* __restrict__ dinv, const float* __restrict__ bias,
    void* __restrict__ outb, int N)
{
    __shared__ float part[2][256];
    const int tid = threadIdx.x;
    const int nodei = tid >> 7;
    const int half = (tid >> 6) & 1;
    const int l = tid & 63;
    const int wid = blockIdx.x * 2 + nodei;
    const int col = l * 4;
    const bool active = wid < N;

    int beg = 0, end = 0;
    if (active) { beg = offs[wid]; end = offs[wid + 1]; }
    const int mid = beg + ((end - beg + 1) >> 1);
    int e = half ? mid : beg;
    const int ee = half ? end : mid;

    float acc[4] = {0.f, 0.f, 0.f, 0.f};
    if (active && half == 0) {
        float self = dinv[wid] * dinv[wid];
        ushort4 r = *(const ushort4*)(hw + (size_t)wid * 256 + col);
        acc[0] = self * b2f(r.x); acc[1] = self * b2f(r.y);
        acc[2] = self * b2f(r.z); acc[3] = self * b2f(r.w);
    }

    for (; e + 7 < ee; e += 8) {
        int2 q[8];
#pragma unroll
        for (int j = 0; j < 8; ++j) q[j] = pk[e + j];
        ushort4 r[8];
#pragma unroll
        for (int j = 0; j < 8; ++j) r[j] = *(const ushort4*)(hw + (size_t)q[j].x * 256 + col);
#pragma unroll
        for (int j = 0; j < 8; ++j) {
            float n = __int_as_float(q[j].y);
            acc[0] = fmaf(n, b2f(r[j].x), acc[0]); acc[1] = fmaf(n, b2f(r[j].y), acc[1]);
            acc[2] = fmaf(n, b2f(r[j].z), acc[2]); acc[3] = fmaf(n, b2f(r[j].w), acc[3]);
        }
    }
    for (; e < ee; ++e) {
        int2 p0 = pk[e];
        float n0 = __int_as_float(p0.y);
        ushort4 r0 = *(const ushort4*)(hw + (size_t)p0.x * 256 + col);
        acc[0] = fmaf(n0, b2f(r0.x), acc[0]); acc[1] = fmaf(n0, b2f(r0.y), acc[1]);
        acc[2] = fmaf(n0, b2f(r0.z), acc[2]); acc[3] = fmaf(n0, b2f(r0.w), acc[3]);
    }

    if (half == 1) {
        float4 v; v.x = acc[0]; v.y = acc[1]; v.z = acc[2]; v.w = acc[3];
        *(float4*)&part[nodei][col] = v;
    }
    __syncthreads();
    if (active && half == 0) {
        float4 pv = *(const float4*)&part[nodei][col];
        acc[0] += pv.x; acc[1] += pv.y; acc[2] += pv.z; acc[3] += pv.w;
#pragma unroll
        for (int jj = 0; jj < 4; ++jj) {
            acc[jj] += bias[col + jj];
            if (ACT == 1) acc[jj] = relu_f(acc[jj]);
        }
        if (OUTBF == 1) {
            ushortt* ob = (ushortt*)outb;
            ushort4 r;
            r.x = bf16rn(acc[0]); r.y = bf16rn(acc[1]); r.z = bf16rn(acc[2]); r.w = bf16rn(acc[3]);
            *(ushort4*)(ob + (size_t)wid * 256 + col) = r;
        } else {
            float* ob = (float*)outb;
            float4 r; r.x = acc[0]; r.y = acc[1]; r.z = acc[2]; r.w = acc[3];
            *(float4*)(ob + (size_t)wid * 256 + col) = r;
        }
    }
}

// ================= GCN gather F=128 ================
__global__ __launch_bounds__(256) void gcn_gather128(
    const int* __restrict__ offs, const int2* __restrict__ pk,
    const ushortt* __restrict__ hw,
    const float* __restrict__ dinv, const float* __restrict__ bias,
    float* __restrict__ outb, int N)
{
    const int wid = blockIdx.x * 4 + (threadIdx.x >> 6);
    const int lane = threadIdx.x & 63;
    if (wid >= N) return;
    const int g = lane >> 5;
    const int col = (lane & 31) * 4;

    float acc[4] = {0.f, 0.f, 0.f, 0.f};
    if (g == 0) {
        float self = dinv[wid] * dinv[wid];
        ushort4 r = *(const ushort4*)(hw + (size_t)wid * 128 + col);
        acc[0] = self * b2f(r.x); acc[1] = self * b2f(r.y);
        acc[2] = self * b2f(r.z); acc[3] = self * b2f(r.w);
    }

    const int beg = offs[wid], end = offs[wid + 1];
    int e = beg + g;
    for (; e + 6 < end; e += 8) {
        int2 q[4];
        q[0] = pk[e]; q[1] = pk[e + 2]; q[2] = pk[e + 4]; q[3] = pk[e + 6];
        ushort4 r[4];
#pragma unroll
        for (int j = 0; j < 4; ++j) r[j] = *(const ushort4*)(hw + (size_t)q[j].x * 128 + col);
#pragma unroll
        for (int j = 0; j < 4; ++j) {
            float n = __int_as_float(q[j].y);
            acc[0] = fmaf(n, b2f(r[j].x), acc[0]); acc[1] = fmaf(n, b2f(r[j].y), acc[1]);
            acc[2] = fmaf(n, b2f(r[j].z), acc[2]); acc[3] = fmaf(n, b2f(r[j].w), acc[3]);
        }
    }
    for (; e < end; e += 2) {
        int2 p0 = pk[e];
        float n0 = __int_as_float(p0.y);
        ushort4 r0 = *(const ushort4*)(hw + (size_t)p0.x * 128 + col);
        acc[0] = fmaf(n0, b2f(r0.x), acc[0]); acc[1] = fmaf(n0, b2f(r0.y), acc[1]);
        acc[2] = fmaf(n0, b2f(r0.z), acc[2]); acc[3] = fmaf(n0, b2f(r0.w), acc[3]);
    }

#pragma unroll
    for (int jj = 0; jj < 4; ++jj)
        acc[jj] += __shfl_xor(acc[jj], 32);

    if (g == 0) {
        float4 r;
        r.x = acc[0] + bias[col + 0];
        r.y = acc[1] + bias[col + 1];
        r.z = acc[2] + bias[col + 2];
        r.w = acc[3] + bias[col + 3];
        *(float4*)(outb + (size_t)wid * 128 + col) = r;
    }
}

// ================= launch ================
extern "C" void kernel_launch(void* const* d_in, const int* in_sizes, int n_in,
                              void* d_out, int out_size, void* d_ws, size_t ws_size,
                              hipStream_t stream)
{
    const float* x    = (const float*)d_in[0];
    const int*   ei   = (const int*)d_in[1];
    const float* w_go = (const float*)d_in[2];
    const float* b_go = (const float*)d_in[3];
    const float* w_re = (const float*)d_in[4];
    const float* b_re = (const float*)d_in[5];
    const float* w_me = (const float*)d_in[6];
    const float* b_me = (const float*)d_in[7];
    const float* w_gw = (const float*)d_in[8];
    const float* b_gw = (const float*)d_in[9];
    const float* ipw  = (const float*)d_in[10];
    const float* ipb  = (const float*)d_in[11];
    const float* opw  = (const float*)d_in[12];
    const float* opb  = (const float*)d_in[13];
    const float* w1   = (const float*)d_in[14];
    const float* b1   = (const float*)d_in[15];
    const float* w2   = (const float*)d_in[16];
    const float* b2   = (const float*)d_in[17];
    float* out = (float*)d_out;
    char* ws   = (char*)d_ws;

    size_t off = 0;
    auto alloc = [&](size_t bytes) { size_t o = off; off += (bytes + 255) & ~(size_t)255; return o; };
    const size_t o_dinv = alloc(NN * 4);
    const size_t o_deg  = alloc(NN * 4);
    const size_t o_offs = alloc((NN + 1) * 4);
    const size_t o_rank = alloc((size_t)NE * 4);
    const size_t o_btot = alloc(64 * 4);
    const size_t o_csrp = alloc((size_t)NE * 8);
    const size_t o_wgo  = alloc(256 * 512 * 2);
    const size_t o_wre  = alloc(256 * 256 * 2);
    const size_t o_wme  = alloc(256 * 256 * 2);
    const size_t o_ipw  = alloc(512 * 256 * 2);
    const size_t o_wv   = alloc(256 * 256 * 2);
    const size_t o_T    = alloc(256 * 256 * 4);
    const size_t o_Tt   = alloc(256 * 256 * 2);
    const size_t o_bbig = alloc(256 * 4);
    const size_t o_w2t  = alloc(128 * 256 * 2);
    const size_t o_pbr  = alloc((size_t)4 * NN * 256 * 2);
    const size_t o_x16  = alloc((size_t)NN * 1024 * 2);
    const size_t o_pbar = alloc((size_t)NN * 1024 * 2);
    const size_t o_obar = alloc((size_t)NN * 256 * 2);
    const size_t o_hw   = alloc((size_t)NN * 256 * 2);
    const size_t o_h1   = alloc((size_t)NN * 256 * 2);
    const size_t o_hw2  = alloc((size_t)NN * 128 * 2);

    float* f_dinv = (float*)(ws + o_dinv);
    int*   i_deg  = (int*)(ws + o_deg);
    int*   i_offs = (int*)(ws + o_offs);
    int*   i_rank = (int*)(ws + o_rank);
    int*   i_btot = (int*)(ws + o_btot);
    int2*  i_csrp = (int2*)(ws + o_csrp);
    float* f_T    = (float*)(ws + o_T);
    float* f_bbig = (float*)(ws + o_bbig);
    ushortt* p    = (ushortt*)(ws + o_pbr);
    ushortt* ago  = (ushortt*)(ws + o_x16);
    ushortt* are  = ago + (size_t)NN * 512;
    ushortt* ame  = ago + (size_t)NN * 768;
    ushortt* pbar = (ushortt*)(ws + o_pbar);
    ushortt* obar = (ushortt*)(ws + o_obar);
    ushortt* hw   = (ushortt*)(ws + o_hw);
    ushortt* h1   = (ushortt*)(ws + o_h1);
    ushortt* hw2  = (ushortt*)(ws + o_hw2);

    const int NB_SCAN = (NN + 1023) / 1024;

    hipMemsetAsync(i_deg, 0, NN * 4, stream);

    // ---- mega_a2: conv_x | conv_all(+wv) | gw | prep_T ----
    mega_a2<<<39676, 256, 0, stream>>>(
        x,
        w_go, w_re, w_me, w2, ipw,
        (ushortt*)(ws + o_wgo), (ushortt*)(ws + o_wre), (ushortt*)(ws + o_wme),
        (ushortt*)(ws + o_w2t), (ushortt*)(ws + o_ipw), (ushortt*)(ws + o_wv),
        ago, are, ame,
        w_gw, b_gw, p,
        opw, w1, f_T);

    // ---- mega_b2: deg histogram + rank capture hidden under branch GEMMs ----
    mega_b2<<<1563 + 2346, 256, 0, stream>>>(
        ei + NE, i_deg, i_rank,
        ago, are, ame,
        (ushortt*)(ws + o_wgo), (ushortt*)(ws + o_wre), (ushortt*)(ws + o_wme),
        b_go, b_re, b_me, p);

    // ---- mega_c: Tt16 | bbig | dinv ----
    mega_c<<<453, 256, 0, stream>>>(
        f_T, (ushortt*)(ws + o_Tt),
        opb, w1, f_bbig,
        i_deg, f_dinv);

    // ---- scan chain ----
    scan_blk<<<NB_SCAN, 1024, 0, stream>>>(i_deg, i_offs, i_btot, NN);
    scan_tot<<<1, 64, 0, stream>>>(i_btot, NB_SCAN);
    scan_add<<<(NN + 1 + 255) / 256, 256, 0, stream>>>(i_btot, i_offs, NN, NB_SCAN);

    // ---- mega_d: atomic-free csr_fill overlapped with fused_attn ----
    mega_d<<<1563 + NN / 8, 256, 0, stream>>>(
        ei, i_offs, i_rank, i_csrp, f_dinv,
        p, (ushortt*)(ws + o_ipw), ipb, pbar);

    // ---- obar = per-head pbar @ wv^T + bv  (factored; was K=1024 Wbig GEMM) ----
    dim3 gOB(1, (NN + 127) / 128, 4);
    gemm_obar<<<gOB, 256, 0, stream>>>(pbar, (ushortt*)(ws + o_wv), ipb, obar);

    // ---- hw = obar @ T + opb@w1 ----
    dim3 gB(2, (NN + 127) / 128);
    gemm_mfma<0><<<gB, 256, 0, stream>>>(obar, 256, (ushortt*)(ws + o_Tt), hw, 256, f_bbig, NN, 256);

    // ---- GCN layer 1 ----
    gcn_gather256<1, 1><<<(NN + 1) / 2, 256, 0, stream>>>(i_offs, i_csrp, hw, f_dinv, b1, h1, NN);

    // ---- GCN layer 2 ----
    dim3 gH2(1, (NN + 127) / 128);
    gemm_mfma<0><<<gH2, 256, 0, stream>>>(h1, 256, (ushortt*)(ws + o_w2t), hw2, 128, nullptr, NN, 256);
    gcn_gather128<<<(NN + 3) / 4, 256, 0, stream>>>(i_offs, i_csrp, hw2, f_dinv, b2, out, NN);
}

// Round 19
// 640.319 us; speedup vs baseline: 1.0153x; 1.0153x over previous
//
#include <hip/hip_runtime.h>
#include <cstdint>
#include <cstddef>

#define NN 50000
#define NE 1600000
#define XD 1025

typedef unsigned short ushortt;
typedef __attribute__((ext_vector_type(8))) short short8;
typedef __attribute__((ext_vector_type(4))) float f32x4;

__device__ __forceinline__ float relu_f(float v) { return v > 0.f ? v : 0.f; }
__device__ __forceinline__ float b2f(ushortt u) { return __uint_as_float(((unsigned)u) << 16); }
__device__ __forceinline__ float blo(unsigned u) { return __uint_as_float(u << 16); }
__device__ __forceinline__ float bhi(unsigned u) { return __uint_as_float(u & 0xffff0000u); }
__device__ __forceinline__ ushortt bf16rn(float f) {
    unsigned u = __float_as_uint(f);
    return (ushortt)((u + 0x7fffu + ((u >> 16) & 1u)) >> 16);
}
__device__ __forceinline__ void load_lds16(const void* g, void* l) {
    __builtin_amdgcn_global_load_lds(
        (const __attribute__((address_space(1))) void*)g,
        (__attribute__((address_space(3))) void*)l, 16, 0, 0);
}

// ================= bf16 MFMA GEMM =================
template <int ACT>
__global__ __launch_bounds__(256) void gemm_mfma(
    const ushortt* __restrict__ A, int lda,
    const ushortt* __restrict__ Bt,
    ushortt* __restrict__ C, int ldc,
    const float* __restrict__ bias,
    int M, int K)
{
    __shared__ ushortt As[128 * 32];
    __shared__ ushortt Bs[128 * 32];
    const int tid = threadIdx.x;
    const int w = tid >> 6, l = tid & 63;
    const int wr = w >> 1, wc = w & 1;
    const int brow = blockIdx.y << 7;
    const int bcol = blockIdx.x << 7;

    f32x4 acc[4][4] = {};

    const int rA0 = wr * 64 + (l & 15);
    const int rB0 = wc * 64 + (l & 15);
    const int kslot = l >> 4;

    for (int k0 = 0; k0 < K; k0 += 32) {
#pragma unroll
        for (int c = 0; c < 2; ++c) {
            int rl = c * 64 + w * 16 + (l >> 2);
            int csel = (l & 3) ^ (rl & 3);
            int gr = brow + rl; if (gr >= M) gr = M - 1;
            load_lds16(A + (size_t)gr * lda + k0 + csel * 8, &As[(c * 64 + w * 16) * 32]);
        }
#pragma unroll
        for (int c = 0; c < 2; ++c) {
            int rl = c * 64 + w * 16 + (l >> 2);
            int csel = (l & 3) ^ (rl & 3);
            load_lds16(Bt + (size_t)(bcol + rl) * K + k0 + csel * 8, &Bs[(c * 64 + w * 16) * 32]);
        }
        __syncthreads();

        short8 af[4], bf[4];
#pragma unroll
        for (int mi = 0; mi < 4; ++mi) {
            int row = rA0 + mi * 16;
            af[mi] = *(const short8*)&As[row * 32 + ((kslot ^ (row & 3)) << 3)];
        }
#pragma unroll
        for (int ni = 0; ni < 4; ++ni) {
            int row = rB0 + ni * 16;
            bf[ni] = *(const short8*)&Bs[row * 32 + ((kslot ^ (row & 3)) << 3)];
        }
#pragma unroll
        for (int mi = 0; mi < 4; ++mi)
#pragma unroll
            for (int ni = 0; ni < 4; ++ni)
                acc[mi][ni] = __builtin_amdgcn_mfma_f32_16x16x32_bf16(af[mi], bf[ni], acc[mi][ni], 0, 0, 0);
        __syncthreads();
    }

    const int cb = bcol + wc * 64 + (l & 15);
    const int rb = brow + wr * 64 + ((l >> 4) << 2);
#pragma unroll
    for (int mi = 0; mi < 4; ++mi) {
#pragma unroll
        for (int ni = 0; ni < 4; ++ni) {
            int col = cb + ni * 16;
            float bv = bias ? bias[col] : 0.f;
#pragma unroll
            for (int r = 0; r < 4; ++r) {
                int row = rb + mi * 16 + r;
                if (row < M) {
                    float v = acc[mi][ni][r] + bv;
                    if (ACT == 1) v = relu_f(v);
                    C[(size_t)row * ldc + col] = bf16rn(v);
                }
            }
        }
    }
}

// ================= per-head obar GEMM: 128x64 tile, 4 waves stacked in M ================
// obar[n, z*64+d] = sum_k pbar[n, z*256+k] * wv16[(z*64+d)*256+k] + ipb[512+z*64+d]
// grid (1, ceil(NN/128), 4)
__global__ __launch_bounds__(256) void gemm_obar(
    const ushortt* __restrict__ pbar,
    const ushortt* __restrict__ wv16,
    const float* __restrict__ ipb,
    ushortt* __restrict__ obar)
{
    __shared__ ushortt As[128 * 32];
    __shared__ ushortt Bs[64 * 32];
    const int tid = threadIdx.x;
    const int w = tid >> 6, l = tid & 63;
    const int z = blockIdx.z;
    const int brow = blockIdx.y << 7;
    const ushortt* Bt = wv16 + (size_t)z * 64 * 256;

    f32x4 acc[2][4] = {};
    const int rA0 = w * 32 + (l & 15);
    const int kslot = l >> 4;

    for (int k0 = 0; k0 < 256; k0 += 32) {
#pragma unroll
        for (int c = 0; c < 2; ++c) {
            int rl = c * 64 + w * 16 + (l >> 2);
            int csel = (l & 3) ^ (rl & 3);
            int gr = brow + rl; if (gr >= NN) gr = NN - 1;
            load_lds16(pbar + (size_t)gr * 1024 + z * 256 + k0 + csel * 8, &As[(c * 64 + w * 16) * 32]);
        }
        {
            int rl = w * 16 + (l >> 2);
            int csel = (l & 3) ^ (rl & 3);
            load_lds16(Bt + (size_t)rl * 256 + k0 + csel * 8, &Bs[(w * 16) * 32]);
        }
        __syncthreads();

        short8 af[2], bf[4];
#pragma unroll
        for (int mi = 0; mi < 2; ++mi) {
            int row = rA0 + mi * 16;
            af[mi] = *(const short8*)&As[row * 32 + ((kslot ^ (row & 3)) << 3)];
        }
#pragma unroll
        for (int ni = 0; ni < 4; ++ni) {
            int row = ni * 16 + (l & 15);
            bf[ni] = *(const short8*)&Bs[row * 32 + ((kslot ^ (row & 3)) << 3)];
        }
#pragma unroll
        for (int mi = 0; mi < 2; ++mi)
#pragma unroll
            for (int ni = 0; ni < 4; ++ni)
                acc[mi][ni] = __builtin_amdgcn_mfma_f32_16x16x32_bf16(af[mi], bf[ni], acc[mi][ni], 0, 0, 0);
        __syncthreads();
    }

    const int rb = brow + w * 32 + ((l >> 4) << 2);
#pragma unroll
    for (int mi = 0; mi < 2; ++mi) {
#pragma unroll
        for (int ni = 0; ni < 4; ++ni) {
            int col = ni * 16 + (l & 15);
            float bv = ipb[512 + z * 64 + col];
#pragma unroll
            for (int r = 0; r < 4; ++r) {
                int row = rb + mi * 16 + r;
                if (row < NN)
                    obar[(size_t)row * 256 + z * 64 + col] = bf16rn(acc[mi][ni][r] + bv);
            }
        }
    }
}

// ================= mega_a2: conv_x | conv_all(+wv) | gw | prep_T ================
// [0,25000) conv_x | [25000,26920) conv_all | [26920,39420) gw | [39420,39676) prep_T
__global__ __launch_bounds__(256) void mega_a2(
    const float* __restrict__ x,
    const float* __restrict__ w_go, const float* __restrict__ w_re,
    const float* __restrict__ w_me, const float* __restrict__ w2,
    const float* __restrict__ ipw,
    ushortt* __restrict__ o_go, ushortt* __restrict__ o_re,
    ushortt* __restrict__ o_me, ushortt* __restrict__ o_w2, ushortt* __restrict__ o_ip,
    ushortt* __restrict__ o_wv,
    ushortt* __restrict__ ago, ushortt* __restrict__ are, ushortt* __restrict__ ame,
    const float* __restrict__ w_gw, const float* __restrict__ b_gw, ushortt* __restrict__ p,
    const float* __restrict__ opw, const float* __restrict__ w1, float* __restrict__ T)
{
    const int bid = blockIdx.x;
    const int tid = threadIdx.x;
    if (bid < 25000) {
        long idx = bid * 256L + tid;
        int n = (int)(idx >> 7);
        int c8 = ((int)idx & 127) << 3;
        const float* src = x + (size_t)n * XD + c8;
        ushortt* dstp;
        if (c8 < 512) dstp = ago + (size_t)n * 512 + c8;
        else if (c8 < 768) dstp = are + (size_t)n * 256 + (c8 - 512);
        else dstp = ame + (size_t)n * 256 + (c8 - 768);
        ushort4 o1, o2;
        o1.x = bf16rn(src[0]); o1.y = bf16rn(src[1]); o1.z = bf16rn(src[2]); o1.w = bf16rn(src[3]);
        o2.x = bf16rn(src[4]); o2.y = bf16rn(src[5]); o2.z = bf16rn(src[6]); o2.w = bf16rn(src[7]);
        *(ushort4*)dstp = o1;
        *(ushort4*)(dstp + 4) = o2;
    } else if (bid < 26920) {
        int idx = (bid - 25000) * 256 + tid;
        if (idx < 131072) {
            int c = idx >> 9, r = idx & 511;
            o_go[idx] = bf16rn(w_go[r * 256 + c]);
        } else if (idx < 196608) {
            int j = idx - 131072; int c = j >> 8, r = j & 255;
            o_re[j] = bf16rn(w_re[r * 256 + c]);
        } else if (idx < 262144) {
            int j = idx - 196608; int c = j >> 8, r = j & 255;
            o_me[j] = bf16rn(w_me[r * 256 + c]);
        } else if (idx < 294912) {
            int j = idx - 262144; int c = j >> 8, r = j & 255;
            o_w2[j] = bf16rn(w2[r * 128 + c]);
        } else if (idx < 425984) {
            int j5 = idx - 294912;
            int j  = j5 & 7;
            int l  = (j5 >> 3) & 63;
            int qk = (j5 >> 9) & 1;
            int ni = (j5 >> 10) & 3;
            int kk = (j5 >> 12) & 7;
            int w  = (j5 >> 15) & 3;
            int row = qk * 256 + w * 64 + ni * 16 + (l & 15);
            int col = kk * 32 + ((l >> 4) << 3) + j;
            o_ip[j5] = bf16rn(ipw[(size_t)row * 256 + col]);
        } else if (idx < 491520) {
            int j6 = idx - 425984;
            o_wv[j6] = bf16rn(ipw[512 * 256 + j6]);
        }
    } else if (bid < 39420) {
        long idx = (bid - 26920) * 256L + tid;
        int n = (int)(idx >> 6);
        int c = ((int)idx & 63) << 2;
        float g = x[(size_t)n * XD + 1024];
        float4 w4 = *(const float4*)(w_gw + c);
        float4 b4 = *(const float4*)(b_gw + c);
        ushort4 r;
        r.x = bf16rn(relu_f(fmaf(g, w4.x, b4.x)));
        r.y = bf16rn(relu_f(fmaf(g, w4.y, b4.y)));
        r.z = bf16rn(relu_f(fmaf(g, w4.z, b4.z)));
        r.w = bf16rn(relu_f(fmaf(g, w4.w, b4.w)));
        *(ushort4*)(p + (size_t)n * 1024 + 768 + c) = r;
    } else {
        int d = bid - 39420, c = tid;
        float a = 0.f;
        for (int j = 0; j < 256; ++j)
            a = fmaf(opw[j * 256 + d], w1[j * 256 + c], a);
        T[d * 256 + c] = a;
    }
}

// ================= mega_b2: deg histogram + RANK capture, then branch GEMMs ================
__global__ __launch_bounds__(256) void mega_b2(
    const int* __restrict__ dst, int* __restrict__ deg, int* __restrict__ rank,
    const ushortt* __restrict__ ago, const ushortt* __restrict__ are, const ushortt* __restrict__ ame,
    const ushortt* __restrict__ wgo, const ushortt* __restrict__ wre, const ushortt* __restrict__ wme,
    const float* __restrict__ b_go, const float* __restrict__ b_re, const float* __restrict__ b_me,
    ushortt* __restrict__ p)
{
    __shared__ ushortt As[128 * 32];
    __shared__ ushortt Bs[128 * 32];
    const int bid = blockIdx.x;
    const int tid = threadIdx.x;

    if (bid < 1563) {
        int e = (bid * 256 + tid) * 4;
        if (e < NE) {
            int4 d = *(const int4*)(dst + e);
            int4 r;
            r.x = atomicAdd(&deg[d.x], 1);
            r.y = atomicAdd(&deg[d.y], 1);
            r.z = atomicAdd(&deg[d.z], 1);
            r.w = atomicAdd(&deg[d.w], 1);
            *(int4*)(rank + e) = r;
        }
        return;
    }

    const int t = bid - 1563;
    const int z = t / 782;
    const int r = t - z * 782;
    const int by = r >> 1;
    const int bx = r & 1;

    const ushortt* A; const ushortt* Bt; const float* bias; int K, lda, coff;
    if (z == 0)      { A = ago; Bt = wgo; bias = b_go; K = 512; lda = 512; coff = 0; }
    else if (z == 1) { A = are; Bt = wre; bias = b_re; K = 256; lda = 256; coff = 256; }
    else             { A = ame; Bt = wme; bias = b_me; K = 256; lda = 256; coff = 512; }

    const int w = tid >> 6, l = tid & 63;
    const int wr = w >> 1, wc = w & 1;
    const int brow = by << 7;
    const int bcol = bx << 7;

    f32x4 acc[4][4] = {};

    const int rA0 = wr * 64 + (l & 15);
    const int rB0 = wc * 64 + (l & 15);
    const int kslot = l >> 4;

    for (int k0 = 0; k0 < K; k0 += 32) {
#pragma unroll
        for (int c = 0; c < 2; ++c) {
            int rl = c * 64 + w * 16 + (l >> 2);
            int csel = (l & 3) ^ (rl & 3);
            int gr = brow + rl; if (gr >= NN) gr = NN - 1;
            load_lds16(A + (size_t)gr * lda + k0 + csel * 8, &As[(c * 64 + w * 16) * 32]);
        }
#pragma unroll
        for (int c = 0; c < 2; ++c) {
            int rl = c * 64 + w * 16 + (l >> 2);
            int csel = (l & 3) ^ (rl & 3);
            load_lds16(Bt + (size_t)(bcol + rl) * K + k0 + csel * 8, &Bs[(c * 64 + w * 16) * 32]);
        }
        __syncthreads();

        short8 af[4], bf[4];
#pragma unroll
        for (int mi = 0; mi < 4; ++mi) {
            int row = rA0 + mi * 16;
            af[mi] = *(const short8*)&As[row * 32 + ((kslot ^ (row & 3)) << 3)];
        }
#pragma unroll
        for (int ni = 0; ni < 4; ++ni) {
            int row = rB0 + ni * 16;
            bf[ni] = *(const short8*)&Bs[row * 32 + ((kslot ^ (row & 3)) << 3)];
        }
#pragma unroll
        for (int mi = 0; mi < 4; ++mi)
#pragma unroll
            for (int ni = 0; ni < 4; ++ni)
                acc[mi][ni] = __builtin_amdgcn_mfma_f32_16x16x32_bf16(af[mi], bf[ni], acc[mi][ni], 0, 0, 0);
        __syncthreads();
    }

    const int cb = bcol + wc * 64 + (l & 15);
    const int rb = brow + wr * 64 + ((l >> 4) << 2);
#pragma unroll
    for (int mi = 0; mi < 4; ++mi) {
#pragma unroll
        for (int ni = 0; ni < 4; ++ni) {
            int col = cb + ni * 16;
            float bv = bias[col];
#pragma unroll
            for (int rr = 0; rr < 4; ++rr) {
                int row = rb + mi * 16 + rr;
                if (row < NN)
                    p[(size_t)row * 1024 + coff + col] = bf16rn(relu_f(acc[mi][ni][rr] + bv));
            }
        }
    }
}

// ================= mega_c: Tt16 transpose | prep_bbig (opb@w1 only) | dinv ================
__global__ __launch_bounds__(256) void mega_c(
    const float* __restrict__ T, ushortt* __restrict__ Tt16,
    const float* __restrict__ opb, const float* __restrict__ w1,
    float* __restrict__ bbig,
    const int* __restrict__ deg, float* __restrict__ dinv)
{
    const int bid = blockIdx.x;
    const int tid = threadIdx.x;
    if (bid < 256) {
        // Tt16[c*256+d] = bf16(T[d*256+c]); c = bid, d = tid
        Tt16[bid * 256 + tid] = bf16rn(T[tid * 256 + bid]);
    } else if (bid == 256) {
        int c = tid;
        float a = 0.f;
        for (int j = 0; j < 256; ++j) a = fmaf(opb[j], w1[j * 256 + c], a);
        bbig[c] = a;
    } else {
        int n = (bid - 257) * 256 + tid;
        if (n < NN) dinv[n] = rsqrtf((float)deg[n] + 1.0f);
    }
}

// ================= scan kernels ================
__global__ __launch_bounds__(1024) void scan_blk(
    const int* __restrict__ deg, int* __restrict__ offs, int* __restrict__ btot, int N)
{
    __shared__ int wsum[16];
    const int tid = threadIdx.x;
    const int lane = tid & 63;
    const int w = tid >> 6;
    int i = blockIdx.x * 1024 + tid;
    int v = (i < N) ? deg[i] : 0;
    int x = v;
#pragma unroll
    for (int d = 1; d < 64; d <<= 1) {
        int t = __shfl_up(x, d);
        if (lane >= d) x += t;
    }
    if (lane == 63) wsum[w] = x;
    __syncthreads();
    if (w == 0 && lane < 16) {
        int y = wsum[lane];
#pragma unroll
        for (int d = 1; d < 16; d <<= 1) {
            int t = __shfl_up(y, d);
            if (lane >= d) y += t;
        }
        wsum[lane] = y;
    }
    __syncthreads();
    int waveoff = (w == 0) ? 0 : wsum[w - 1];
    if (i < N) offs[i] = waveoff + x - v;
    if (tid == 0) btot[blockIdx.x] = wsum[15];
}

__global__ __launch_bounds__(64) void scan_tot(int* __restrict__ btot, int nb)
{
    int t = threadIdx.x;
    int v = (t < nb) ? btot[t] : 0;
    int x = v;
#pragma unroll
    for (int d = 1; d < 64; d <<= 1) {
        int tt = __shfl_up(x, d);
        if (t >= d) x += tt;
    }
    if (t < nb) btot[t] = x - v;
    if (t == 63) btot[nb] = x;
}

__global__ __launch_bounds__(256) void scan_add(
    const int* __restrict__ btot, int* __restrict__ offs, int N, int nb)
{
    int i = blockIdx.x * 256 + threadIdx.x;
    if (i < N) offs[i] += btot[i >> 10];
    else if (i == N) offs[N] = btot[nb];
}

// ================= mega_d: atomic-free csr_fill | fused_attn_v7 ================
__global__ __launch_bounds__(256) void mega_d(
    const int* __restrict__ ei, const int* __restrict__ offs,
    const int* __restrict__ rank, int2* __restrict__ pk, const float* __restrict__ dinv,
    const ushortt* __restrict__ p,
    const ushortt* __restrict__ ipw_opt,
    const float* __restrict__ ipb,
    ushortt* __restrict__ pbar)
{
    __shared__ __align__(16) ushortt p_s[32 * 256];
    __shared__ float asum_s[8][4][4];

    const int bid = blockIdx.x;
    const int tid = threadIdx.x;

    if (bid < 1563) {
        int e = (bid * 256 + tid) * 4;
        if (e < NE) {
            int4 s4 = *(const int4*)(ei + e);
            int4 d4 = *(const int4*)(ei + NE + e);
            int4 r4 = *(const int4*)(rank + e);
            pk[offs[d4.x] + r4.x] = make_int2(s4.x, __float_as_int(dinv[s4.x] * dinv[d4.x]));
            pk[offs[d4.y] + r4.y] = make_int2(s4.y, __float_as_int(dinv[s4.y] * dinv[d4.y]));
            pk[offs[d4.z] + r4.z] = make_int2(s4.z, __float_as_int(dinv[s4.z] * dinv[d4.z]));
            pk[offs[d4.w] + r4.w] = make_int2(s4.w, __float_as_int(dinv[s4.w] * dinv[d4.w]));
        }
        return;
    }

    const int w = tid >> 6, l = tid & 63;
    const int nb = (bid - 1563) << 3;
    const size_t r0 = (size_t)nb * 4;

    {
        const int slot = l & 31;
#pragma unroll
        for (int c = 0; c < 4; ++c) {
            int row = w * 8 + c * 2 + (l >> 5);
            load_lds16(p + (r0 + row) * 256 + ((slot ^ (row & 7)) << 3),
                       &p_s[(w * 8 + c * 2) * 256]);
        }
    }
    __syncthreads();

    const int nq = w << 6;
    f32x4 aq[2][4] = {}, ak[2][4] = {};
    const int ar0 = l & 15, ar1 = ar0 + 16;
#pragma unroll
    for (int kk = 0; kk < 8; ++kk) {
        const int slot = (kk << 2) + (l >> 4);
        short8 a0 = *(const short8*)&p_s[ar0 * 256 + ((slot ^ (ar0 & 7)) << 3)];
        short8 a1 = *(const short8*)&p_s[ar1 * 256 + ((slot ^ (ar1 & 7)) << 3)];
        short8 bq[4], bk[4];
#pragma unroll
        for (int ni = 0; ni < 4; ++ni) {
            const size_t base = ((((size_t)(w * 8 + kk)) * 4 + ni) * 2) * 512 + (size_t)l * 8;
            bq[ni] = *(const short8*)&ipw_opt[base];
            bk[ni] = *(const short8*)&ipw_opt[base + 512];
        }
#pragma unroll
        for (int ni = 0; ni < 4; ++ni) {
            aq[0][ni] = __builtin_amdgcn_mfma_f32_16x16x32_bf16(a0, bq[ni], aq[0][ni], 0, 0, 0);
            aq[1][ni] = __builtin_amdgcn_mfma_f32_16x16x32_bf16(a1, bq[ni], aq[1][ni], 0, 0, 0);
            ak[0][ni] = __builtin_amdgcn_mfma_f32_16x16x32_bf16(a0, bk[ni], ak[0][ni], 0, 0, 0);
            ak[1][ni] = __builtin_amdgcn_mfma_f32_16x16x32_bf16(a1, bk[ni], ak[1][ni], 0, 0, 0);
        }
    }

    float bqv[4], bkv[4];
#pragma unroll
    for (int ni = 0; ni < 4; ++ni) {
        int col = nq + (ni << 4) + (l & 15);
        bqv[ni] = ipb[col];
        bkv[ni] = ipb[256 + col];
    }
#pragma unroll
    for (int mt = 0; mt < 2; ++mt) {
        float s[4][4] = {};
#pragma unroll
        for (int ni = 0; ni < 4; ++ni) {
            float qv[4], kv[4];
#pragma unroll
            for (int r = 0; r < 4; ++r) {
                qv[r] = aq[mt][ni][r] + bqv[ni];
                kv[r] = ak[mt][ni][r] + bkv[ni];
            }
#pragma unroll
            for (int ti = 0; ti < 4; ++ti)
#pragma unroll
                for (int tj = 0; tj < 4; ++tj)
                    s[ti][tj] = fmaf(qv[ti], kv[tj], s[ti][tj]);
        }
#pragma unroll
        for (int m = 1; m <= 8; m <<= 1)
#pragma unroll
            for (int ti = 0; ti < 4; ++ti)
#pragma unroll
                for (int tj = 0; tj < 4; ++tj)
                    s[ti][tj] += __shfl_xor(s[ti][tj], m);
        float asum[4] = {};
#pragma unroll
        for (int ti = 0; ti < 4; ++ti) {
            float v0 = s[ti][0] * 0.125f, v1 = s[ti][1] * 0.125f;
            float v2 = s[ti][2] * 0.125f, v3 = s[ti][3] * 0.125f;
            float m4 = fmaxf(fmaxf(v0, v1), fmaxf(v2, v3));
            float e0 = __expf(v0 - m4), e1 = __expf(v1 - m4);
            float e2 = __expf(v2 - m4), e3 = __expf(v3 - m4);
            float inv = 1.f / (e0 + e1 + e2 + e3);
            asum[0] = fmaf(e0, inv, asum[0]);
            asum[1] = fmaf(e1, inv, asum[1]);
            asum[2] = fmaf(e2, inv, asum[2]);
            asum[3] = fmaf(e3, inv, asum[3]);
        }
        if ((l & 15) == 0) {
            int node = mt * 4 + (l >> 4);
#pragma unroll
            for (int tj = 0; tj < 4; ++tj)
                asum_s[node][w][tj] = 0.25f * asum[tj];
        }
    }
    __syncthreads();

    {
        const int node = tid >> 5;
        const int c8 = (tid & 31) << 3;
        float f[4][8];
#pragma unroll
        for (int tj = 0; tj < 4; ++tj) {
            int row = node * 4 + tj;
            uint4 u = *(const uint4*)&p_s[row * 256 + (((c8 >> 3) ^ (row & 7)) << 3)];
            f[tj][0] = blo(u.x); f[tj][1] = bhi(u.x); f[tj][2] = blo(u.y); f[tj][3] = bhi(u.y);
            f[tj][4] = blo(u.z); f[tj][5] = bhi(u.z); f[tj][6] = blo(u.w); f[tj][7] = bhi(u.w);
        }
#pragma unroll
        for (int h = 0; h < 4; ++h) {
            float a0 = asum_s[node][h][0], a1 = asum_s[node][h][1];
            float a2 = asum_s[node][h][2], a3 = asum_s[node][h][3];
            ushortt res[8];
#pragma unroll
            for (int i = 0; i < 8; ++i)
                res[i] = bf16rn(a0 * f[0][i] + a1 * f[1][i] + a2 * f[2][i] + a3 * f[3][i]);
            *(uint4*)&pbar[(size_t)(nb + node) * 1024 + h * 256 + c8] = *(uint4*)res;
        }
    }
}

// ================= GCN gather F=256 ================
template <int ACT, int OUTBF>
__global__ __launch_bounds__(256) void gcn_gather256(
    const int* __restrict__ offs, const int2* __restrict__ pk,
    const ushortt* __restrict__ hw,
    const float* __restrict__ dinv, const float* __restrict__ bias,
    void* __restrict__ outb, int N)
{
    __shared__ float part[2][256];
    const int tid = threadIdx.x;
    const int nodei = tid >> 7;
    const int half = (tid >> 6) & 1;
    const int l = tid & 63;
    const int wid = blockIdx.x * 2 + nodei;
    const int col = l * 4;
    const bool active = wid < N;

    int beg = 0, end = 0;
    if (active) { beg = offs[wid]; end = offs[wid + 1]; }
    const int mid = beg + ((end - beg + 1) >> 1);
    int e = half ? mid : beg;
    const int ee = half ? end : mid;

    float acc[4] = {0.f, 0.f, 0.f, 0.f};
    if (active && half == 0) {
        float self = dinv[wid] * dinv[wid];
        ushort4 r = *(const ushort4*)(hw + (size_t)wid * 256 + col);
        acc[0] = self * b2f(r.x); acc[1] = self * b2f(r.y);
        acc[2] = self * b2f(r.z); acc[3] = self * b2f(r.w);
    }

    for (; e + 7 < ee; e += 8) {
        int2 q[8];
#pragma unroll
        for (int j = 0; j < 8; ++j) q[j] = pk[e + j];
        ushort4 r[8];
#pragma unroll
        for (int j = 0; j < 8; ++j) r[j] = *(const ushort4*)(hw + (size_t)q[j].x * 256 + col);
#pragma unroll
        for (int j = 0; j < 8; ++j) {
            float n = __int_as_float(q[j].y);
            acc[0] = fmaf(n, b2f(r[j].x), acc[0]); acc[1] = fmaf(n, b2f(r[j].y), acc[1]);
            acc[2] = fmaf(n, b2f(r[j].z), acc[2]); acc[3] = fmaf(n, b2f(r[j].w), acc[3]);
        }
    }
    for (; e < ee; ++e) {
        int2 p0 = pk[e];
        float n0 = __int_as_float(p0.y);
        ushort4 r0 = *(const ushort4*)(hw + (size_t)p0.x * 256 + col);
        acc[0] = fmaf(n0, b2f(r0.x), acc[0]); acc[1] = fmaf(n0, b2f(r0.y), acc[1]);
        acc[2] = fmaf(n0, b2f(r0.z), acc[2]); acc[3] = fmaf(n0, b2f(r0.w), acc[3]);
    }

    if (half == 1) {
        float4 v; v.x = acc[0]; v.y = acc[1]; v.z = acc[2]; v.w = acc[3];
        *(float4*)&part[nodei][col] = v;
    }
    __syncthreads();
    if (active && half == 0) {
        float4 pv = *(const float4*)&part[nodei][col];
        acc[0] += pv.x; acc[1] += pv.y; acc[2] += pv.z; acc[3] += pv.w;
#pragma unroll
        for (int jj = 0; jj < 4; ++jj) {
            acc[jj] += bias[col + jj];
            if (ACT == 1) acc[jj] = relu_f(acc[jj]);
        }
        if (OUTBF == 1) {
            ushortt* ob = (ushortt*)outb;
            ushort4 r;
            r.x = bf16rn(acc[0]); r.y = bf16rn(acc[1]); r.z = bf16rn(acc[2]); r.w = bf16rn(acc[3]);
            *(ushort4*)(ob + (size_t)wid * 256 + col) = r;
        } else {
            float* ob = (float*)outb;
            float4 r; r.x = acc[0]; r.y = acc[1]; r.z = acc[2]; r.w = acc[3];
            *(float4*)(ob + (size_t)wid * 256 + col) = r;
        }
    }
}

// ================= GCN gather F=128 ================
__global__ __launch_bounds__(256) void gcn_gather128(
    const int* __restrict__ offs, const int2* __restrict__ pk,
    const ushortt* __restrict__ hw,
    const float* __restrict__ dinv, const float* __restrict__ bias,
    float* __restrict__ outb, int N)
{
    const int wid = blockIdx.x * 4 + (threadIdx.x >> 6);
    const int lane = threadIdx.x & 63;
    if (wid >= N) return;
    const int g = lane >> 5;
    const int col = (lane & 31) * 4;

    float acc[4] = {0.f, 0.f, 0.f, 0.f};
    if (g == 0) {
        float self = dinv[wid] * dinv[wid];
        ushort4 r = *(const ushort4*)(hw + (size_t)wid * 128 + col);
        acc[0] = self * b2f(r.x); acc[1] = self * b2f(r.y);
        acc[2] = self * b2f(r.z); acc[3] = self * b2f(r.w);
    }

    const int beg = offs[wid], end = offs[wid + 1];
    int e = beg + g;
    for (; e + 6 < end; e += 8) {
        int2 q[4];
        q[0] = pk[e]; q[1] = pk[e + 2]; q[2] = pk[e + 4]; q[3] = pk[e + 6];
        ushort4 r[4];
#pragma unroll
        for (int j = 0; j < 4; ++j) r[j] = *(const ushort4*)(hw + (size_t)q[j].x * 128 + col);
#pragma unroll
        for (int j = 0; j < 4; ++j) {
            float n = __int_as_float(q[j].y);
            acc[0] = fmaf(n, b2f(r[j].x), acc[0]); acc[1] = fmaf(n, b2f(r[j].y), acc[1]);
            acc[2] = fmaf(n, b2f(r[j].z), acc[2]); acc[3] = fmaf(n, b2f(r[j].w), acc[3]);
        }
    }
    for (; e < end; e += 2) {
        int2 p0 = pk[e];
        float n0 = __int_as_float(p0.y);
        ushort4 r0 = *(const ushort4*)(hw + (size_t)p0.x * 128 + col);
        acc[0] = fmaf(n0, b2f(r0.x), acc[0]); acc[1] = fmaf(n0, b2f(r0.y), acc[1]);
        acc[2] = fmaf(n0, b2f(r0.z), acc[2]); acc[3] = fmaf(n0, b2f(r0.w), acc[3]);
    }

#pragma unroll
    for (int jj = 0; jj < 4; ++jj)
        acc[jj] += __shfl_xor(acc[jj], 32);

    if (g == 0) {
        float4 r;
        r.x = acc[0] + bias[col + 0];
        r.y = acc[1] + bias[col + 1];
        r.z = acc[2] + bias[col + 2];
        r.w = acc[3] + bias[col + 3];
        *(float4*)(outb + (size_t)wid * 128 + col) = r;
    }
}

// ================= launch ================
extern "C" void kernel_launch(void* const* d_in, const int* in_sizes, int n_in,
                              void* d_out, int out_size, void* d_ws, size_t ws_size,
                              hipStream_t stream)
{
    const float* x    = (const float*)d_in[0];
    const int*   ei   = (const int*)d_in[1];
    const float* w_go = (const float*)d_in[2];
    const float* b_go = (const float*)d_in[3];
    const float* w_re = (const float*)d_in[4];
    const float* b_re = (const float*)d_in[5];
    const float* w_me = (const float*)d_in[6];
    const float* b_me = (const float*)d_in[7];
    const float* w_gw = (const float*)d_in[8];
    const float* b_gw = (const float*)d_in[9];
    const float* ipw  = (const float*)d_in[10];
    const float* ipb  = (const float*)d_in[11];
    const float* opw  = (const float*)d_in[12];
    const float* opb  = (const float*)d_in[13];
    const float* w1   = (const float*)d_in[14];
    const float* b1   = (const float*)d_in[15];
    const float* w2   = (const float*)d_in[16];
    const float* b2   = (const float*)d_in[17];
    float* out = (float*)d_out;
    char* ws   = (char*)d_ws;

    size_t off = 0;
    auto alloc = [&](size_t bytes) { size_t o = off; off += (bytes + 255) & ~(size_t)255; return o; };
    const size_t o_dinv = alloc(NN * 4);
    const size_t o_deg  = alloc(NN * 4);
    const size_t o_offs = alloc((NN + 1) * 4);
    const size_t o_rank = alloc((size_t)NE * 4);
    const size_t o_btot = alloc(64 * 4);
    const size_t o_csrp = alloc((size_t)NE * 8);
    const size_t o_wgo  = alloc(256 * 512 * 2);
    const size_t o_wre  = alloc(256 * 256 * 2);
    const size_t o_wme  = alloc(256 * 256 * 2);
    const size_t o_ipw  = alloc(512 * 256 * 2);
    const size_t o_wv   = alloc(256 * 256 * 2);
    const size_t o_T    = alloc(256 * 256 * 4);
    const size_t o_Tt   = alloc(256 * 256 * 2);
    const size_t o_bbig = alloc(256 * 4);
    const size_t o_w2t  = alloc(128 * 256 * 2);
    const size_t o_pbr  = alloc((size_t)4 * NN * 256 * 2);
    const size_t o_x16  = alloc((size_t)NN * 1024 * 2);
    const size_t o_pbar = alloc((size_t)NN * 1024 * 2);
    const size_t o_obar = alloc((size_t)NN * 256 * 2);
    const size_t o_hw   = alloc((size_t)NN * 256 * 2);
    const size_t o_h1   = alloc((size_t)NN * 256 * 2);
    const size_t o_hw2  = alloc((size_t)NN * 128 * 2);

    float* f_dinv = (float*)(ws + o_dinv);
    int*   i_deg  = (int*)(ws + o_deg);
    int*   i_offs = (int*)(ws + o_offs);
    int*   i_rank = (int*)(ws + o_rank);
    int*   i_btot = (int*)(ws + o_btot);
    int2*  i_csrp = (int2*)(ws + o_csrp);
    float* f_T    = (float*)(ws + o_T);
    float* f_bbig = (float*)(ws + o_bbig);
    ushortt* p    = (ushortt*)(ws + o_pbr);
    ushortt* ago  = (ushortt*)(ws + o_x16);
    ushortt* are  = ago + (size_t)NN * 512;
    ushortt* ame  = ago + (size_t)NN * 768;
    ushortt* pbar = (ushortt*)(ws + o_pbar);
    ushortt* obar = (ushortt*)(ws + o_obar);
    ushortt* hw   = (ushortt*)(ws + o_hw);
    ushortt* h1   = (ushortt*)(ws + o_h1);
    ushortt* hw2  = (ushortt*)(ws + o_hw2);

    const int NB_SCAN = (NN + 1023) / 1024;

    hipMemsetAsync(i_deg, 0, NN * 4, stream);

    // ---- mega_a2: conv_x | conv_all(+wv) | gw | prep_T ----
    mega_a2<<<39676, 256, 0, stream>>>(
        x,
        w_go, w_re, w_me, w2, ipw,
        (ushortt*)(ws + o_wgo), (ushortt*)(ws + o_wre), (ushortt*)(ws + o_wme),
        (ushortt*)(ws + o_w2t), (ushortt*)(ws + o_ipw), (ushortt*)(ws + o_wv),
        ago, are, ame,
        w_gw, b_gw, p,
        opw, w1, f_T);

    // ---- mega_b2: deg histogram + rank capture hidden under branch GEMMs ----
    mega_b2<<<1563 + 2346, 256, 0, stream>>>(
        ei + NE, i_deg, i_rank,
        ago, are, ame,
        (ushortt*)(ws + o_wgo), (ushortt*)(ws + o_wre), (ushortt*)(ws + o_wme),
        b_go, b_re, b_me, p);

    // ---- mega_c: Tt16 | bbig | dinv ----
    mega_c<<<453, 256, 0, stream>>>(
        f_T, (ushortt*)(ws + o_Tt),
        opb, w1, f_bbig,
        i_deg, f_dinv);

    // ---- scan chain ----
    scan_blk<<<NB_SCAN, 1024, 0, stream>>>(i_deg, i_offs, i_btot, NN);
    scan_tot<<<1, 64, 0, stream>>>(i_btot, NB_SCAN);
    scan_add<<<(NN + 1 + 255) / 256, 256, 0, stream>>>(i_btot, i_offs, NN, NB_SCAN);

    // ---- mega_d: atomic-free csr_fill overlapped with fused_attn ----
    mega_d<<<1563 + NN / 8, 256, 0, stream>>>(
        ei, i_offs, i_rank, i_csrp, f_dinv,
        p, (ushortt*)(ws + o_ipw), ipb, pbar);

    // ---- obar = per-head pbar @ wv^T + bv  (factored; was K=1024 Wbig GEMM) ----
    dim3 gOB(1, (NN + 127) / 128, 4);
    gemm_obar<<<gOB, 256, 0, stream>>>(pbar, (ushortt*)(ws + o_wv), ipb, obar);

    // ---- hw = obar @ T + opb@w1 ----
    dim3 gB(2, (NN + 127) / 128);
    gemm_mfma<0><<<gB, 256, 0, stream>>>(obar, 256, (ushortt*)(ws + o_Tt), hw, 256, f_bbig, NN, 256);

    // ---- GCN layer 1 ----
    gcn_gather256<1, 1><<<(NN + 1) / 2, 256, 0, stream>>>(i_offs, i_csrp, hw, f_dinv, b1, h1, NN);

    // ---- GCN layer 2 ----
    dim3 gH2(1, (NN + 127) / 128);
    gemm_mfma<0><<<gH2, 256, 0, stream>>>(h1, 256, (ushortt*)(ws + o_w2t), hw2, 128, nullptr, NN, 256);
    gcn_gather128<<<(NN + 3) / 4, 256, 0, stream>>>(i_offs, i_csrp, hw2, f_dinv, b2, out, NN);
}